// Round 4
// baseline (292.544 us; speedup 1.0000x reference)
//
#include <hip/hip_runtime.h>

// Problem constants
#define G_GRAPHS 1024
#define N_NODES  40
#define M_EDGES  780          // N*(N-1)/2
#define NUM_NODES (G_GRAPHS * N_NODES)          // 40960
#define H_ELEMS  (NUM_NODES * 64)               // 2621440
#define X_STRIDE 160
#define X_PER_G  25600
#define SLOPE 0.1f

#define PACK_PER_MLP 9216     // W0(4096) + W1(4096) + W2(1024) bf16 elems

typedef __bf16 bf16x8 __attribute__((ext_vector_type(8)));
typedef unsigned short us8 __attribute__((ext_vector_type(8)));
typedef float f32x4 __attribute__((ext_vector_type(4)));

__device__ __forceinline__ float lrelu(float v) { return fmaxf(v, SLOPE * v); }
__device__ __forceinline__ unsigned short f2bf(float x) {
    __bf16 b = (__bf16)x;                       // RNE convert
    return __builtin_bit_cast(unsigned short, b);
}
__device__ __forceinline__ unsigned int pk2bf(float a, float b) {
    return (unsigned int)f2bf(a) | ((unsigned int)f2bf(b) << 16);
}

// ---------------------------------------------------------------------------
// K0: pack MLP weights (bf16) in d_ws. Layout serves the A-frag role:
// element for lane l, reg j, tile (mt,kt) of W^T is
// W[kt*32 + ((l>>4)&3)*8 + j][mt*16 + (l&15)]  -> linear ((mt*2+kt)*64+l)*8+j.
// W2 padded 10->16 cols (zeros). [0..9215] edge MLP, [9216..18431] node MLP.
// ---------------------------------------------------------------------------
__global__ __launch_bounds__(256) void k_prep(const float* __restrict__ We0,
                                              const float* __restrict__ We1,
                                              const float* __restrict__ We2,
                                              const float* __restrict__ Wn0,
                                              const float* __restrict__ Wn1,
                                              const float* __restrict__ Wn2,
                                              unsigned short* __restrict__ wp) {
    int t = blockIdx.x * 256 + threadIdx.x;     // 0..18431 (72 blocks)
    int mlp = t / PACK_PER_MLP;
    int o = t - mlp * PACK_PER_MLP;
    const float* W0 = mlp ? Wn0 : We0;
    const float* W1 = mlp ? Wn1 : We1;
    const float* W2 = mlp ? Wn2 : We2;
    float val;
    if (o < 8192) {
        const float* W = (o < 4096) ? W0 : W1;
        int idx = o & 4095;
        int j = idx & 7, l = (idx >> 3) & 63, tt = idx >> 9;   // tt = mt*2+kt
        int kt = tt & 1, mt = tt >> 1;
        int k = kt * 32 + ((l >> 4) & 3) * 8 + j;
        int m = mt * 16 + (l & 15);
        val = W[k * 64 + m];
    } else {
        int idx = o - 8192;                      // 0..1023, mt=0 only
        int j = idx & 7, l = (idx >> 3) & 63, kt = idx >> 9;
        int k = kt * 32 + ((l >> 4) & 3) * 8 + j;
        int m = l & 15;
        val = (m < 10) ? W2[k * 10 + m] : 0.f;
    }
    wp[mlp * PACK_PER_MLP + o] = f2bf(val);
}

// ---------------------------------------------------------------------------
// MLP chunk machinery. Round-4 change: GEMM3 writes to a per-wave 1.5 KB
// mini-buffer (32 rows x 12 f32) and the SAME wave immediately scatters the
// X 4x4 blocks for its 32 rows (lane-pair roles, as in rounds 0/1). No
// block barrier, no sEP arena, no tail sweep.
// ---------------------------------------------------------------------------
struct ChunkRegs {
    bf16x8 A1[4][2];
    bf16x8 A2[4][2];
    bf16x8 A3[2];
    float4 bv0[4];
    float4 bv1[4];
    float  bz[4];
};

__device__ __forceinline__ void run_chunk(int R0, int w, int l,
                                          const float4* sh4,
                                          unsigned short* sB,
                                          float* miniw,      // wave's 32x12 f32
                                          float* Xg,
                                          const ChunkRegs& cr) {
    const int nl = l & 15;
    const int rq = (l >> 4) & 3;
    const int rl = l >> 1;            // row within wave's 32-row slice
    const int hf2 = l & 1;            // feature-half / scatter role
    const int row = R0 + rl;

    const bool is_e = (row < 780);
    const bool is_n = (row >= 800 && row < 840);
    int ii = 0, jj = 0;
    if (is_e) {
        // closed-form inverse of cum(i) = 39i - i(i-1)/2 (exact in fp32)
        float tq = 6241.0f - 8.0f * (float)row;
        int i0 = (int)(0.5f * (79.0f - sqrtf(tq)));
        i0 = min(38, max(0, i0));
        int cum = 39 * i0 - ((i0 * (i0 - 1)) >> 1);
        if (cum > row) { --i0; cum = 39 * i0 - ((i0 * (i0 - 1)) >> 1); }
        else if (row - cum >= 39 - i0) { cum += 39 - i0; ++i0; }
        ii = i0; jj = i0 + 1 + (row - cum);
    } else if (is_n) {
        ii = jj = row - 800;
    }                                  // else dummy row (780..799)

    // ---- E build: row, features [hf2*32, hf2*32+32) -> sB (swizzled) ----
    {
        unsigned short tmp[32];
#pragma unroll
        for (int q = 0; q < 8; q++) {
            int u = hf2 * 8 + q;
            float4 a = sh4[ii * 16 + (u ^ ((ii & 7) << 1))];
            if (is_e) {
                float4 bq = sh4[jj * 16 + (u ^ ((jj & 7) << 1))];
                a.x += bq.x; a.y += bq.y; a.z += bq.z; a.w += bq.w;
            }
            tmp[4 * q + 0] = f2bf(a.x); tmp[4 * q + 1] = f2bf(a.y);
            tmp[4 * q + 2] = f2bf(a.z); tmp[4 * q + 3] = f2bf(a.w);
        }
        int r_sb = 32 * w + rl;
#pragma unroll
        for (int q = 0; q < 4; q++) {
            int cs = (hf2 * 4 + q) ^ (r_sb & 7);
            *(us8*)((char*)sB + r_sb * 128 + cs * 16) = *(const us8*)(tmp + 8 * q);
        }
    }

    // B-frag (activations) from LDS: node fixed, k = kt*32+rq*8+j contiguous
    auto ZB = [&](int nt, int kt) -> bf16x8 {
        int node = 32 * w + nt * 16 + nl;
        int cs = (kt * 4 + rq) ^ (node & 7);
        return __builtin_bit_cast(bf16x8,
            *(const us8*)((const char*)sB + node * 128 + cs * 16));
    };
    auto zstore = [&](int mt, int nt, const f32x4& v) {
        int node = 32 * w + nt * 16 + nl;
        int cs = (mt * 2 + (rq >> 1)) ^ (node & 7);
        uint2 u = make_uint2(pk2bf(v[0], v[1]), pk2bf(v[2], v[3]));
        *(uint2*)((char*)sB + node * 128 + cs * 16 + (rq & 1) * 8) = u;
    };

    // ---- GEMM1: Z1 = lrelu(E @ W0 + b0) -> sB (in place) ----
    {
        bf16x8 B[2][2];
#pragma unroll
        for (int nt = 0; nt < 2; nt++)
#pragma unroll
            for (int kt = 0; kt < 2; kt++) B[nt][kt] = ZB(nt, kt);
#pragma unroll
        for (int mt = 0; mt < 4; mt++) {
            float4 bv = cr.bv0[mt];
#pragma unroll
            for (int nt = 0; nt < 2; nt++) {
                f32x4 acc = (f32x4){0.f, 0.f, 0.f, 0.f};
                acc = __builtin_amdgcn_mfma_f32_16x16x32_bf16(cr.A1[mt][0], B[nt][0], acc, 0, 0, 0);
                acc = __builtin_amdgcn_mfma_f32_16x16x32_bf16(cr.A1[mt][1], B[nt][1], acc, 0, 0, 0);
                f32x4 z;
                z[0] = lrelu(acc[0] + bv.x); z[1] = lrelu(acc[1] + bv.y);
                z[2] = lrelu(acc[2] + bv.z); z[3] = lrelu(acc[3] + bv.w);
                zstore(mt, nt, z);
            }
        }
    }

    // ---- GEMM2: Z2 = lrelu(Z1 @ W1 + b1) -> sB (in place) ----
    {
        bf16x8 B[2][2];
#pragma unroll
        for (int nt = 0; nt < 2; nt++)
#pragma unroll
            for (int kt = 0; kt < 2; kt++) B[nt][kt] = ZB(nt, kt);
#pragma unroll
        for (int mt = 0; mt < 4; mt++) {
            float4 bv = cr.bv1[mt];
#pragma unroll
            for (int nt = 0; nt < 2; nt++) {
                f32x4 acc = (f32x4){0.f, 0.f, 0.f, 0.f};
                acc = __builtin_amdgcn_mfma_f32_16x16x32_bf16(cr.A2[mt][0], B[nt][0], acc, 0, 0, 0);
                acc = __builtin_amdgcn_mfma_f32_16x16x32_bf16(cr.A2[mt][1], B[nt][1], acc, 0, 0, 0);
                f32x4 z;
                z[0] = lrelu(acc[0] + bv.x); z[1] = lrelu(acc[1] + bv.y);
                z[2] = lrelu(acc[2] + bv.z); z[3] = lrelu(acc[3] + bv.w);
                zstore(mt, nt, z);
            }
        }
    }

    // ---- GEMM3: EP = Z2 @ W2 + b2 -> miniw (f32, stride 12 floats) ----
    {
        bf16x8 B[2][2];
#pragma unroll
        for (int nt = 0; nt < 2; nt++)
#pragma unroll
            for (int kt = 0; kt < 2; kt++) B[nt][kt] = ZB(nt, kt);
#pragma unroll
        for (int nt = 0; nt < 2; nt++) {
            f32x4 acc = (f32x4){0.f, 0.f, 0.f, 0.f};
            acc = __builtin_amdgcn_mfma_f32_16x16x32_bf16(cr.A3[0], B[nt][0], acc, 0, 0, 0);
            acc = __builtin_amdgcn_mfma_f32_16x16x32_bf16(cr.A3[1], B[nt][1], acc, 0, 0, 0);
            int rl2 = nt * 16 + nl;
            if (rq < 3) {
                float* p = miniw + rl2 * 12 + rq * 4;
                *(float2*)p = make_float2(acc[0] + cr.bz[0], acc[1] + cr.bz[1]);
                if (rq < 2)
                    *(float2*)(p + 2) = make_float2(acc[2] + cr.bz[2], acc[3] + cr.bz[3]);
            }
        }
    }

    // ---- scatter: this wave's 32 rows -> X 4x4 block(s), lane-pair roles ----
    {
        const float* ep = miniw + rl * 12;
        float2 e0 = *(const float2*)(ep + 0);
        float2 e1 = *(const float2*)(ep + 2);
        float2 e2 = *(const float2*)(ep + 4);
        float2 e3 = *(const float2*)(ep + 6);
        float2 e4 = *(const float2*)(ep + 8);
        float f0 = e0.x, f1 = e0.y, f2 = e1.x, f3 = e1.y;
        float f4 = e2.x, f5 = e2.y, f6 = e3.x, f7 = e3.y;
        float f8 = e4.x, f9 = e4.y;
        float4 r0 = make_float4(f0, f1, f2, f3);
        float4 r1 = make_float4(f1, f4, f5, f6);
        float4 r2 = make_float4(f2, f5, f7, f8);
        float4 r3 = make_float4(f3, f6, f8, f9);
        if (is_e) {
            int bi = hf2 ? jj : ii, bj = hf2 ? ii : jj;   // block symmetric
            float* p = Xg + (4 * bi) * X_STRIDE + 4 * bj;
            *(float4*)(p + 0 * X_STRIDE) = r0;
            *(float4*)(p + 1 * X_STRIDE) = r1;
            *(float4*)(p + 2 * X_STRIDE) = r2;
            *(float4*)(p + 3 * X_STRIDE) = r3;
        } else if (is_n) {
            float* p = Xg + (4 * ii + hf2 * 2) * X_STRIDE + 4 * ii;
            if (hf2 == 0) {
                *(float4*)(p + 0 * X_STRIDE) = r0;
                *(float4*)(p + 1 * X_STRIDE) = r1;
            } else {
                *(float4*)(p + 0 * X_STRIDE) = r2;
                *(float4*)(p + 1 * X_STRIDE) = r3;
            }
        }
    }
}

// ---------------------------------------------------------------------------
// K1 (fused): GCN + MLP + per-wave X scatter, one graph per block.
// LDS arena: EXACTLY 32768 B -> 4 blocks/CU (VGPR<=128 via launch_bounds).
//   [0,     10240)  sh   : final h, 40x64 f32, swizzled  | GCN: h0@0, P@1024
//   [10240, 26624)  sB   : 128x64 bf16 GEMM ping         | GCN: buf@10240,
//                          h1@20480, S@25600 (1KB hole; S dead in MLP phase,
//                          overlapped sB rows 120-127 only used after GCN)
//   [26624, 32768)  mini : 4 waves x 32x12 f32 EP rows   | GCN: h2@26624
// Round-3 post-mortem: score = kernel_time + ~132us fixed harness overhead;
// k_fused is latency-bound at 2 waves/SIMD (VALU 29%, Mfma 6.5%, HBM 24%).
// This round doubles resident waves (2->4 blocks/CU) and removes the barrier
// + tail sweep so X stores spread across the whole kernel.
// ---------------------------------------------------------------------------
__global__ __launch_bounds__(256, 4) void k_fused(const float* __restrict__ x,
                                                  const float* __restrict__ Wg0,
                                                  const float* __restrict__ bg0,
                                                  const float* __restrict__ Wg1,
                                                  const float* __restrict__ bg1,
                                                  const float* __restrict__ Wg2,
                                                  const float* __restrict__ bg2,
                                                  const unsigned short* __restrict__ wp,
                                                  const float* __restrict__ be0,
                                                  const float* __restrict__ be1,
                                                  const float* __restrict__ be2,
                                                  const float* __restrict__ bn0,
                                                  const float* __restrict__ bn1,
                                                  const float* __restrict__ bn2,
                                                  float* __restrict__ hout,
                                                  float* __restrict__ X) {
    __shared__ __align__(16) char smem[32768];
    float* sh          = (float*)smem;                      // [0,10240)
    unsigned short* sB = (unsigned short*)(smem + 10240);   // [10240,26624)
    float* mini        = (float*)(smem + 26624);            // [26624,32768)
    // GCN-phase aliases
    float* h0  = (float*)smem;                              // [0,960)
    float* P   = (float*)(smem + 1024);                     // [1024,3072)
    float* buf = (float*)(smem + 10240);                    // [10240,20480)
    float* h1  = (float*)(smem + 20480);                    // [20480,25600)
    float* S   = (float*)(smem + 25600);                    // [25600,25856)
    float* h2  = (float*)(smem + 26624);                    // [26624,31744)

    const int g = blockIdx.x;
    const int tid = threadIdx.x;
    const int l = tid & 63;
    const int w = tid >> 6;
    const float inv39 = 1.0f / 39.0f;
    const int c32 = tid & 31;
    const int c64 = tid & 63;
    const int rq = (l >> 4) & 3;

    // =========================== GCN phase ===========================
    {
        float w0c[6], w1c[32], w2c[32];
#pragma unroll
        for (int f = 0; f < 6; f++)  w0c[f] = Wg0[f * 32 + c32];
#pragma unroll
        for (int m = 0; m < 32; m++) w1c[m] = Wg1[m * 32 + c32];
#pragma unroll
        for (int m = 0; m < 32; m++) w2c[m] = Wg2[m * 64 + c64];
        const float b0c = bg0[c32];
        const float b1c = bg1[c32];
        const float b2c = bg2[c64];

        for (int idx = tid; idx < N_NODES * 6; idx += 256) {
            int n = idx / 6, f = idx - n * 6;
            h0[idx] = x[(g * N_NODES + n) * 16 + f];
        }
        __syncthreads();

        // ---- layer 0 ----
        {
            int n0 = tid >> 5;
#pragma unroll
            for (int t = 0; t < 5; t++) {
                int n = n0 + 8 * t;
                float s = 0.f;
#pragma unroll
                for (int f = 0; f < 6; f++) s += h0[n * 6 + f] * w0c[f];
                buf[n * 32 + c32] = s;
            }
        }
        __syncthreads();
        { int grp = tid >> 5; float s = 0.f;
#pragma unroll
          for (int n = grp * 5; n < grp * 5 + 5; n++) s += buf[n * 32 + c32];
          P[grp * 32 + c32] = s; }
        __syncthreads();
        if (tid < 32) { float s = 0.f;
#pragma unroll
          for (int grp = 0; grp < 8; grp++) s += P[grp * 32 + tid];
          S[tid] = s; }
        __syncthreads();
        for (int idx = tid; idx < N_NODES * 32; idx += 256)
            h1[idx] = lrelu((S[c32] - buf[idx]) * inv39 + b0c);
        __syncthreads();

        // ---- layer 1 ----
        {
            int n0 = tid >> 5;
#pragma unroll
            for (int t = 0; t < 5; t++) {
                int n = n0 + 8 * t;
                const float4* hp = (const float4*)(h1 + n * 32);
                float s = 0.f;
#pragma unroll
                for (int q = 0; q < 8; q++) {
                    float4 hv = hp[q];
                    s += hv.x * w1c[4 * q + 0] + hv.y * w1c[4 * q + 1]
                       + hv.z * w1c[4 * q + 2] + hv.w * w1c[4 * q + 3];
                }
                buf[n * 32 + c32] = s;
            }
        }
        __syncthreads();
        { int grp = tid >> 5; float s = 0.f;
#pragma unroll
          for (int n = grp * 5; n < grp * 5 + 5; n++) s += buf[n * 32 + c32];
          P[grp * 32 + c32] = s; }
        __syncthreads();
        if (tid < 32) { float s = 0.f;
#pragma unroll
          for (int grp = 0; grp < 8; grp++) s += P[grp * 32 + tid];
          S[tid] = s; }
        __syncthreads();
        for (int idx = tid; idx < N_NODES * 32; idx += 256)
            h2[idx] = lrelu((S[c32] - buf[idx]) * inv39 + b1c);
        __syncthreads();

        // ---- layer 2 ----
        {
            int n0 = tid >> 6;
#pragma unroll
            for (int t = 0; t < 10; t++) {
                int n = n0 + 4 * t;
                const float4* hp = (const float4*)(h2 + n * 32);
                float s = 0.f;
#pragma unroll
                for (int q = 0; q < 8; q++) {
                    float4 hv = hp[q];
                    s += hv.x * w2c[4 * q + 0] + hv.y * w2c[4 * q + 1]
                       + hv.z * w2c[4 * q + 2] + hv.w * w2c[4 * q + 3];
                }
                buf[n * 64 + c64] = s;
            }
        }
        __syncthreads();
        { int grp = tid >> 6; float s = 0.f;
#pragma unroll
          for (int n = grp * 10; n < grp * 10 + 10; n++) s += buf[n * 64 + c64];
          P[grp * 64 + c64] = s; }
        __syncthreads();
        if (tid < 64) { float s = 0.f;
#pragma unroll
          for (int grp = 0; grp < 4; grp++) s += P[grp * 64 + tid];
          S[tid] = s; }
        __syncthreads();

        // ---- epilogue: write hout (global) + sh (LDS, swizzled) ----
        // (clobbers h0/P region - both dead; reads S (safe slot) + buf)
        for (int idx = tid; idx < N_NODES * 64; idx += 256) {
            float v = (S[c64] - buf[idx]) * inv39 + b2c;
            hout[g * N_NODES * 64 + idx] = v;
            int n = idx >> 6;
            int u = c64 >> 2;
            int us = u ^ ((n & 7) << 1);
            sh[n * 64 + us * 4 + (c64 & 3)] = v;
        }
    }
    __syncthreads();   // sh ready; GCN scratch dead

    // =========================== MLP phase ===========================
    const float4* sh4 = (const float4*)sh;
    float* miniw = mini + w * 384;           // wave's 32x12 f32 slice
    float* Xg = X + g * X_PER_G;

    auto WA = [&](const unsigned short* base, int mt, int kt) -> bf16x8 {
        return __builtin_bit_cast(bf16x8,
            *(const us8*)(base + ((mt * 2 + kt) * 64 + l) * 8));
    };
    auto loadW = [&](ChunkRegs& cr, const unsigned short* wb,
                     const float* B0, const float* B1, const float* B2) {
#pragma unroll
        for (int mt = 0; mt < 4; mt++) {
#pragma unroll
            for (int kt = 0; kt < 2; kt++) {
                cr.A1[mt][kt] = WA(wb, mt, kt);
                cr.A2[mt][kt] = WA(wb + 4096, mt, kt);
            }
            cr.bv0[mt] = *(const float4*)(B0 + mt * 16 + rq * 4);
            cr.bv1[mt] = *(const float4*)(B1 + mt * 16 + rq * 4);
        }
        cr.A3[0] = WA(wb + 8192, 0, 0);
        cr.A3[1] = WA(wb + 8192, 0, 1);
#pragma unroll
        for (int k = 0; k < 4; k++) {
            int f = rq * 4 + k;
            cr.bz[k] = (f < 10) ? B2[f] : 0.f;
        }
    };

    ChunkRegs ce;
    loadW(ce, wp, be0, be1, be2);            // edge MLP weights

    // chunk loop: wave-local, no barriers. Node chunks (25,26) are always a
    // wave's LAST iteration -> overwrite ce with node weights in place.
    for (int c = w; c < 27; c += 4) {
        if (c >= 25)
            loadW(ce, wp + PACK_PER_MLP, bn0, bn1, bn2);
        run_chunk(c * 32, w, l, sh4, sB, miniw, Xg, ce);
    }
}

// ---------------------------------------------------------------------------
// Launch
// ---------------------------------------------------------------------------
extern "C" void kernel_launch(void* const* d_in, const int* in_sizes, int n_in,
                              void* d_out, int out_size, void* d_ws, size_t ws_size,
                              hipStream_t stream) {
    const float* x   = (const float*)d_in[0];
    const float* Wg0 = (const float*)d_in[4];
    const float* bg0 = (const float*)d_in[5];
    const float* Wg1 = (const float*)d_in[6];
    const float* bg1 = (const float*)d_in[7];
    const float* Wg2 = (const float*)d_in[8];
    const float* bg2 = (const float*)d_in[9];
    const float* Wn0 = (const float*)d_in[10];
    const float* bn0 = (const float*)d_in[11];
    const float* Wn1 = (const float*)d_in[12];
    const float* bn1 = (const float*)d_in[13];
    const float* Wn2 = (const float*)d_in[14];
    const float* bn2 = (const float*)d_in[15];
    const float* We0 = (const float*)d_in[16];
    const float* be0 = (const float*)d_in[17];
    const float* We1 = (const float*)d_in[18];
    const float* be1 = (const float*)d_in[19];
    const float* We2 = (const float*)d_in[20];
    const float* be2 = (const float*)d_in[21];

    float* hout = (float*)d_out;            // h: 40960 x 64 fp32
    float* X    = hout + H_ELEMS;           // X: 1024 x 160 x 160 fp32
    unsigned short* wp = (unsigned short*)d_ws;  // 18432 bf16 packed weights

    k_prep<<<72, 256, 0, stream>>>(We0, We1, We2, Wn0, Wn1, Wn2, wp);
    k_fused<<<G_GRAPHS, 256, 0, stream>>>(x, Wg0, bg0, Wg1, bg1, Wg2, bg2,
                                          wp, be0, be1, be2, bn0, bn1, bn2,
                                          hout, X);
}

// Round 5
// 209.640 us; speedup vs baseline: 1.3955x; 1.3955x over previous
//
#include <hip/hip_runtime.h>

// Problem constants
#define G_GRAPHS 1024
#define N_NODES  40
#define M_EDGES  780          // N*(N-1)/2
#define NUM_NODES (G_GRAPHS * N_NODES)          // 40960
#define H_ELEMS  (NUM_NODES * 64)               // 2621440
#define X_STRIDE 160
#define X_PER_G  25600
#define SLOPE 0.1f

#define PACK_PER_MLP 9216     // W0(4096) + W1(4096) + W2(1024) bf16 elems

typedef __bf16 bf16x8 __attribute__((ext_vector_type(8)));
typedef unsigned short us8 __attribute__((ext_vector_type(8)));
typedef float f32x4 __attribute__((ext_vector_type(4)));

__device__ __forceinline__ float lrelu(float v) { return fmaxf(v, SLOPE * v); }
__device__ __forceinline__ unsigned short f2bf(float x) {
    __bf16 b = (__bf16)x;                       // RNE convert
    return __builtin_bit_cast(unsigned short, b);
}
__device__ __forceinline__ unsigned int pk2bf(float a, float b) {
    return (unsigned int)f2bf(a) | ((unsigned int)f2bf(b) << 16);
}

// ---------------------------------------------------------------------------
// K0: pack MLP weights (bf16) in d_ws. Layout serves the A-frag role:
// element for lane l, reg j, tile (mt,kt) of W^T is
// W[kt*32 + ((l>>4)&3)*8 + j][mt*16 + (l&15)]  -> linear ((mt*2+kt)*64+l)*8+j.
// W2 padded 10->16 cols (zeros). [0..9215] edge MLP, [9216..18431] node MLP.
// ---------------------------------------------------------------------------
__global__ __launch_bounds__(256) void k_prep(const float* __restrict__ We0,
                                              const float* __restrict__ We1,
                                              const float* __restrict__ We2,
                                              const float* __restrict__ Wn0,
                                              const float* __restrict__ Wn1,
                                              const float* __restrict__ Wn2,
                                              unsigned short* __restrict__ wp) {
    int t = blockIdx.x * 256 + threadIdx.x;     // 0..18431 (72 blocks)
    int mlp = t / PACK_PER_MLP;
    int o = t - mlp * PACK_PER_MLP;
    const float* W0 = mlp ? Wn0 : We0;
    const float* W1 = mlp ? Wn1 : We1;
    const float* W2 = mlp ? Wn2 : We2;
    float val;
    if (o < 8192) {
        const float* W = (o < 4096) ? W0 : W1;
        int idx = o & 4095;
        int j = idx & 7, l = (idx >> 3) & 63, tt = idx >> 9;   // tt = mt*2+kt
        int kt = tt & 1, mt = tt >> 1;
        int k = kt * 32 + ((l >> 4) & 3) * 8 + j;
        int m = mt * 16 + (l & 15);
        val = W[k * 64 + m];
    } else {
        int idx = o - 8192;                      // 0..1023, mt=0 only
        int j = idx & 7, l = (idx >> 3) & 63, kt = idx >> 9;
        int k = kt * 32 + ((l >> 4) & 3) * 8 + j;
        int m = l & 15;
        val = (m < 10) ? W2[k * 10 + m] : 0.f;
    }
    wp[mlp * PACK_PER_MLP + o] = f2bf(val);
}

// ---------------------------------------------------------------------------
// MLP machinery. Round-5: PAIR-ILP — each wave runs TWO independent chunk
// chains (A in sBA, B in sBB: distinct __shared__ objects so the compiler
// can prove non-aliasing and interleave chain B's LDS/VALU into chain A's
// latency stalls). Memory structure (sEP arena + coalesced sweep) is
// byte-identical to round 3 — round 4 proved scattered partial-line X
// writes cause catastrophic L2 RMW amplification (FETCH +149 MB).
// ---------------------------------------------------------------------------
struct ChunkRegs {
    bf16x8 A1[4][2];
    bf16x8 A2[4][2];
    bf16x8 A3[2];
    float4 bv0[4];
    float4 bv1[4];
    float  bz[4];
};

__device__ __forceinline__ void run_pair(int R0A, int R0B, int w, int l,
                                         const float4* sh4,
                                         unsigned short* sBA,
                                         unsigned short* sBB,
                                         float* sEP,
                                         const ChunkRegs& cr) {
    const int nl = l & 15;
    const int rq = (l >> 4) & 3;
    const int rl = l >> 1;            // row within wave's 32-row slice
    const int hf2 = l & 1;            // feature half

    // ---- decode both rows (closed-form triangular inverse, exact fp32) ----
    auto decode = [&](int row, int& ii, int& jj, bool& is_e, bool& is_n) {
        is_e = (row < 780);
        is_n = (row >= 800 && row < 840);
        ii = 0; jj = 0;
        if (is_e) {
            float tq = 6241.0f - 8.0f * (float)row;
            int i0 = (int)(0.5f * (79.0f - sqrtf(tq)));
            i0 = min(38, max(0, i0));
            int cum = 39 * i0 - ((i0 * (i0 - 1)) >> 1);
            if (cum > row) { --i0; cum = 39 * i0 - ((i0 * (i0 - 1)) >> 1); }
            else if (row - cum >= 39 - i0) { cum += 39 - i0; ++i0; }
            ii = i0; jj = i0 + 1 + (row - cum);
        } else if (is_n) {
            ii = jj = row - 800;
        }                              // else dummy row
    };
    int iiA, jjA, iiB, jjB; bool ieA, inA, ieB, inB;
    decode(R0A + rl, iiA, jjA, ieA, inA);
    decode(R0B + rl, iiB, jjB, ieB, inB);

    // ---- E build (A then B; independent chains) ----
    auto ebuild = [&](unsigned short* sB, int ii, int jj, bool is_e) {
        unsigned short tmp[32];
#pragma unroll
        for (int q = 0; q < 8; q++) {
            int u = hf2 * 8 + q;
            float4 a = sh4[ii * 16 + (u ^ ((ii & 7) << 1))];
            if (is_e) {
                float4 bq = sh4[jj * 16 + (u ^ ((jj & 7) << 1))];
                a.x += bq.x; a.y += bq.y; a.z += bq.z; a.w += bq.w;
            }
            tmp[4 * q + 0] = f2bf(a.x); tmp[4 * q + 1] = f2bf(a.y);
            tmp[4 * q + 2] = f2bf(a.z); tmp[4 * q + 3] = f2bf(a.w);
        }
        int r_sb = 32 * w + rl;
#pragma unroll
        for (int q = 0; q < 4; q++) {
            int cs = (hf2 * 4 + q) ^ (r_sb & 7);
            *(us8*)((char*)sB + r_sb * 128 + cs * 16) = *(const us8*)(tmp + 8 * q);
        }
    };
    ebuild(sBA, iiA, jjA, ieA);
    ebuild(sBB, iiB, jjB, ieB);

    // B-frag read / Z store helpers (same swizzle as rounds 0-4)
    auto ZB = [&](const unsigned short* s, int nt, int kt) -> bf16x8 {
        int node = 32 * w + nt * 16 + nl;
        int cs = (kt * 4 + rq) ^ (node & 7);
        return __builtin_bit_cast(bf16x8,
            *(const us8*)((const char*)s + node * 128 + cs * 16));
    };
    auto zstore = [&](unsigned short* s, int mt, int nt, const f32x4& v) {
        int node = 32 * w + nt * 16 + nl;
        int cs = (mt * 2 + (rq >> 1)) ^ (node & 7);
        uint2 u = make_uint2(pk2bf(v[0], v[1]), pk2bf(v[2], v[3]));
        *(uint2*)((char*)s + node * 128 + cs * 16 + (rq & 1) * 8) = u;
    };

    auto gemm_layer = [&](unsigned short* s, const bf16x8 A[4][2],
                          const float4* bv) {
        bf16x8 B[2][2];
#pragma unroll
        for (int nt = 0; nt < 2; nt++)
#pragma unroll
            for (int kt = 0; kt < 2; kt++) B[nt][kt] = ZB(s, nt, kt);
#pragma unroll
        for (int mt = 0; mt < 4; mt++) {
            float4 b = bv[mt];
#pragma unroll
            for (int nt = 0; nt < 2; nt++) {
                f32x4 acc = (f32x4){0.f, 0.f, 0.f, 0.f};
                acc = __builtin_amdgcn_mfma_f32_16x16x32_bf16(A[mt][0], B[nt][0], acc, 0, 0, 0);
                acc = __builtin_amdgcn_mfma_f32_16x16x32_bf16(A[mt][1], B[nt][1], acc, 0, 0, 0);
                f32x4 z;
                z[0] = lrelu(acc[0] + b.x); z[1] = lrelu(acc[1] + b.y);
                z[2] = lrelu(acc[2] + b.z); z[3] = lrelu(acc[3] + b.w);
                zstore(s, mt, nt, z);
            }
        }
    };

    // ---- GEMM1 (Z1), GEMM2 (Z2): A then B per layer ----
    gemm_layer(sBA, cr.A1, cr.bv0);
    gemm_layer(sBB, cr.A1, cr.bv0);
    gemm_layer(sBA, cr.A2, cr.bv1);
    gemm_layer(sBB, cr.A2, cr.bv1);

    // ---- GEMM3: EP -> sEP (f32, stride 10), both chains ----
    auto gemm3 = [&](unsigned short* s, int R0) {
        bf16x8 B[2][2];
#pragma unroll
        for (int nt = 0; nt < 2; nt++)
#pragma unroll
            for (int kt = 0; kt < 2; kt++) B[nt][kt] = ZB(s, nt, kt);
#pragma unroll
        for (int nt = 0; nt < 2; nt++) {
            f32x4 acc = (f32x4){0.f, 0.f, 0.f, 0.f};
            acc = __builtin_amdgcn_mfma_f32_16x16x32_bf16(cr.A3[0], B[nt][0], acc, 0, 0, 0);
            acc = __builtin_amdgcn_mfma_f32_16x16x32_bf16(cr.A3[1], B[nt][1], acc, 0, 0, 0);
            int rowe = R0 + nt * 16 + nl;
            bool valid = (rowe < 780) || (rowe >= 800 && rowe < 840);
            if (valid && rq < 3) {
                int epr = (rowe < 780) ? rowe : rowe - 20;   // nodes -> 780..819
                float* p = sEP + epr * 10 + rq * 4;
                *(float2*)p = make_float2(acc[0] + cr.bz[0], acc[1] + cr.bz[1]);
                if (rq < 2)
                    *(float2*)(p + 2) = make_float2(acc[2] + cr.bz[2], acc[3] + cr.bz[3]);
            }
        }
    };
    gemm3(sBA, R0A);
    gemm3(sBB, R0B);
}

// ---------------------------------------------------------------------------
// K1 (fused): GCN + pair-ILP MLP + coalesced X sweep, one graph per block.
// LDS arena (75,808 B, 2 blocks/CU):
//   [0,     10240)  sh   : final h, 40x64 f32, swizzled | GCN: h0@0, P@1024
//   [10240, 26624)  sBA  : chain-A GEMM ping            | GCN: buf@10240,
//                                                         h1@20480, S@25600
//   [26624, 43008)  sBB  : chain-B GEMM ping            | GCN: h2@26624
//   [43008, 75808)  sEP  : 820x10 f32 MLP outputs
// Round-4 lesson (FETCH 168 MB): X lines must be written fully + tightly ->
// keep the block-wide sweep. This round adds latency-chain ILP instead of
// occupancy: 14 chunk-pairs, each pair one weight set:
//   p<12: (2p, 2p+1) edge;  p=12: (24, 27=dummy) edge;  p=13: (25,26) node.
// ---------------------------------------------------------------------------
__global__ __launch_bounds__(256, 2) void k_fused(const float* __restrict__ x,
                                                  const float* __restrict__ Wg0,
                                                  const float* __restrict__ bg0,
                                                  const float* __restrict__ Wg1,
                                                  const float* __restrict__ bg1,
                                                  const float* __restrict__ Wg2,
                                                  const float* __restrict__ bg2,
                                                  const unsigned short* __restrict__ wp,
                                                  const float* __restrict__ be0,
                                                  const float* __restrict__ be1,
                                                  const float* __restrict__ be2,
                                                  const float* __restrict__ bn0,
                                                  const float* __restrict__ bn1,
                                                  const float* __restrict__ bn2,
                                                  float* __restrict__ hout,
                                                  float* __restrict__ X) {
    __shared__ __align__(16) char smem[75808];
    float* sh           = (float*)smem;                      // [0,10240)
    unsigned short* sBA = (unsigned short*)(smem + 10240);   // [10240,26624)
    unsigned short* sBB = (unsigned short*)(smem + 26624);   // [26624,43008)
    float* sEP          = (float*)(smem + 43008);            // [43008,75808)
    // GCN-phase aliases
    float* h0  = (float*)smem;                               // [0,960)
    float* P   = (float*)(smem + 1024);                      // [1024,3072)
    float* buf = (float*)(smem + 10240);                     // [10240,20480)
    float* h1  = (float*)(smem + 20480);                     // [20480,25600)
    float* S   = (float*)(smem + 25600);                     // [25600,25856)
    float* h2  = (float*)(smem + 26624);                     // [26624,31744)

    const int g = blockIdx.x;
    const int tid = threadIdx.x;
    const int l = tid & 63;
    const int w = tid >> 6;
    const float inv39 = 1.0f / 39.0f;
    const int c32 = tid & 31;
    const int c64 = tid & 63;
    const int rq = (l >> 4) & 3;

    // =========================== GCN phase ===========================
    {
        float w0c[6], w1c[32], w2c[32];
#pragma unroll
        for (int f = 0; f < 6; f++)  w0c[f] = Wg0[f * 32 + c32];
#pragma unroll
        for (int m = 0; m < 32; m++) w1c[m] = Wg1[m * 32 + c32];
#pragma unroll
        for (int m = 0; m < 32; m++) w2c[m] = Wg2[m * 64 + c64];
        const float b0c = bg0[c32];
        const float b1c = bg1[c32];
        const float b2c = bg2[c64];

        for (int idx = tid; idx < N_NODES * 6; idx += 256) {
            int n = idx / 6, f = idx - n * 6;
            h0[idx] = x[(g * N_NODES + n) * 16 + f];
        }
        __syncthreads();

        // ---- layer 0 ----
        {
            int n0 = tid >> 5;
#pragma unroll
            for (int t = 0; t < 5; t++) {
                int n = n0 + 8 * t;
                float s = 0.f;
#pragma unroll
                for (int f = 0; f < 6; f++) s += h0[n * 6 + f] * w0c[f];
                buf[n * 32 + c32] = s;
            }
        }
        __syncthreads();
        { int grp = tid >> 5; float s = 0.f;
#pragma unroll
          for (int n = grp * 5; n < grp * 5 + 5; n++) s += buf[n * 32 + c32];
          P[grp * 32 + c32] = s; }
        __syncthreads();
        if (tid < 32) { float s = 0.f;
#pragma unroll
          for (int grp = 0; grp < 8; grp++) s += P[grp * 32 + tid];
          S[tid] = s; }
        __syncthreads();
        for (int idx = tid; idx < N_NODES * 32; idx += 256)
            h1[idx] = lrelu((S[c32] - buf[idx]) * inv39 + b0c);
        __syncthreads();

        // ---- layer 1 ----
        {
            int n0 = tid >> 5;
#pragma unroll
            for (int t = 0; t < 5; t++) {
                int n = n0 + 8 * t;
                const float4* hp = (const float4*)(h1 + n * 32);
                float s = 0.f;
#pragma unroll
                for (int q = 0; q < 8; q++) {
                    float4 hv = hp[q];
                    s += hv.x * w1c[4 * q + 0] + hv.y * w1c[4 * q + 1]
                       + hv.z * w1c[4 * q + 2] + hv.w * w1c[4 * q + 3];
                }
                buf[n * 32 + c32] = s;
            }
        }
        __syncthreads();
        { int grp = tid >> 5; float s = 0.f;
#pragma unroll
          for (int n = grp * 5; n < grp * 5 + 5; n++) s += buf[n * 32 + c32];
          P[grp * 32 + c32] = s; }
        __syncthreads();
        if (tid < 32) { float s = 0.f;
#pragma unroll
          for (int grp = 0; grp < 8; grp++) s += P[grp * 32 + tid];
          S[tid] = s; }
        __syncthreads();
        for (int idx = tid; idx < N_NODES * 32; idx += 256)
            h2[idx] = lrelu((S[c32] - buf[idx]) * inv39 + b1c);
        __syncthreads();

        // ---- layer 2 ----
        {
            int n0 = tid >> 6;
#pragma unroll
            for (int t = 0; t < 10; t++) {
                int n = n0 + 4 * t;
                const float4* hp = (const float4*)(h2 + n * 32);
                float s = 0.f;
#pragma unroll
                for (int q = 0; q < 8; q++) {
                    float4 hv = hp[q];
                    s += hv.x * w2c[4 * q + 0] + hv.y * w2c[4 * q + 1]
                       + hv.z * w2c[4 * q + 2] + hv.w * w2c[4 * q + 3];
                }
                buf[n * 64 + c64] = s;
            }
        }
        __syncthreads();
        { int grp = tid >> 6; float s = 0.f;
#pragma unroll
          for (int n = grp * 10; n < grp * 10 + 10; n++) s += buf[n * 64 + c64];
          P[grp * 64 + c64] = s; }
        __syncthreads();
        if (tid < 64) { float s = 0.f;
#pragma unroll
          for (int grp = 0; grp < 4; grp++) s += P[grp * 64 + tid];
          S[tid] = s; }
        __syncthreads();

        // ---- epilogue: write hout (global) + sh (LDS, swizzled) ----
        // (clobbers h0/P region - both dead; reads S + buf, not clobbered)
        for (int idx = tid; idx < N_NODES * 64; idx += 256) {
            float v = (S[c64] - buf[idx]) * inv39 + b2c;
            hout[g * N_NODES * 64 + idx] = v;
            int n = idx >> 6;
            int u = c64 >> 2;
            int us = u ^ ((n & 7) << 1);
            sh[n * 64 + us * 4 + (c64 & 3)] = v;
        }
    }
    __syncthreads();   // sh ready; GCN scratch dead

    // =========================== MLP phase ===========================
    const float4* sh4 = (const float4*)sh;

    auto WA = [&](const unsigned short* base, int mt, int kt) -> bf16x8 {
        return __builtin_bit_cast(bf16x8,
            *(const us8*)(base + ((mt * 2 + kt) * 64 + l) * 8));
    };
    auto loadW = [&](ChunkRegs& cr, const unsigned short* wb,
                     const float* B0, const float* B1, const float* B2) {
#pragma unroll
        for (int mt = 0; mt < 4; mt++) {
#pragma unroll
            for (int kt = 0; kt < 2; kt++) {
                cr.A1[mt][kt] = WA(wb, mt, kt);
                cr.A2[mt][kt] = WA(wb + 4096, mt, kt);
            }
            cr.bv0[mt] = *(const float4*)(B0 + mt * 16 + rq * 4);
            cr.bv1[mt] = *(const float4*)(B1 + mt * 16 + rq * 4);
        }
        cr.A3[0] = WA(wb + 8192, 0, 0);
        cr.A3[1] = WA(wb + 8192, 0, 1);
#pragma unroll
        for (int k = 0; k < 4; k++) {
            int f = rq * 4 + k;
            cr.bz[k] = (f < 10) ? B2[f] : 0.f;
        }
    };

    ChunkRegs ce;
    loadW(ce, wp, be0, be1, be2);            // edge MLP weights

    // pair loop: wave-local, no barriers. p=13 (node pair) is always wave
    // 1's LAST pair -> overwrite ce with node weights in place.
    for (int p = w; p < 14; p += 4) {
        int c1, c2;
        if (p < 12)       { c1 = 2 * p; c2 = 2 * p + 1; }   // edge pairs
        else if (p == 12) { c1 = 24;    c2 = 27;        }   // edge + dummy
        else              { c1 = 25;    c2 = 26;            // node pair
                            loadW(ce, wp + PACK_PER_MLP, bn0, bn1, bn2); }
        run_pair(32 * c1, 32 * c2, w, l, sh4, sBA, sBB, sEP, ce);
    }

    __syncthreads();   // all EP rows ready

    // ---- X sweep: thread owns whole 4x4 blocks; coalesced stores ----
    float* Xg = X + g * X_PER_G;
#pragma unroll
    for (int k = 0; k < 7; k++) {
        int b = k * 256 + tid;
        if (b < 1600) {
            int bi = b / 40;
            int bj = b - bi * 40;
            int ridx;
            if (bi == bj) {
                ridx = 780 + bi;
            } else {
                int mn = min(bi, bj), mx = max(bi, bj);
                ridx = 39 * mn - ((mn * (mn - 1)) >> 1) + (mx - mn - 1);
            }
            const float* ep = sEP + ridx * 10;
            float2 e0 = *(const float2*)(ep + 0);
            float2 e1 = *(const float2*)(ep + 2);
            float2 e2 = *(const float2*)(ep + 4);
            float2 e3 = *(const float2*)(ep + 6);
            float2 e4 = *(const float2*)(ep + 8);
            float f0 = e0.x, f1 = e0.y, f2 = e1.x, f3 = e1.y;
            float f4 = e2.x, f5 = e2.y, f6 = e3.x, f7 = e3.y;
            float f8 = e4.x, f9 = e4.y;
            float4 r0 = make_float4(f0, f1, f2, f3);
            float4 r1 = make_float4(f1, f4, f5, f6);
            float4 r2 = make_float4(f2, f5, f7, f8);
            float4 r3 = make_float4(f3, f6, f8, f9);
            float* p = Xg + (4 * bi) * X_STRIDE + 4 * bj;
            *(float4*)(p + 0 * X_STRIDE) = r0;
            *(float4*)(p + 1 * X_STRIDE) = r1;
            *(float4*)(p + 2 * X_STRIDE) = r2;
            *(float4*)(p + 3 * X_STRIDE) = r3;
        }
    }
}

// ---------------------------------------------------------------------------
// Launch
// ---------------------------------------------------------------------------
extern "C" void kernel_launch(void* const* d_in, const int* in_sizes, int n_in,
                              void* d_out, int out_size, void* d_ws, size_t ws_size,
                              hipStream_t stream) {
    const float* x   = (const float*)d_in[0];
    const float* Wg0 = (const float*)d_in[4];
    const float* bg0 = (const float*)d_in[5];
    const float* Wg1 = (const float*)d_in[6];
    const float* bg1 = (const float*)d_in[7];
    const float* Wg2 = (const float*)d_in[8];
    const float* bg2 = (const float*)d_in[9];
    const float* Wn0 = (const float*)d_in[10];
    const float* bn0 = (const float*)d_in[11];
    const float* Wn1 = (const float*)d_in[12];
    const float* bn1 = (const float*)d_in[13];
    const float* Wn2 = (const float*)d_in[14];
    const float* bn2 = (const float*)d_in[15];
    const float* We0 = (const float*)d_in[16];
    const float* be0 = (const float*)d_in[17];
    const float* We1 = (const float*)d_in[18];
    const float* be1 = (const float*)d_in[19];
    const float* We2 = (const float*)d_in[20];
    const float* be2 = (const float*)d_in[21];

    float* hout = (float*)d_out;            // h: 40960 x 64 fp32
    float* X    = hout + H_ELEMS;           // X: 1024 x 160 x 160 fp32
    unsigned short* wp = (unsigned short*)d_ws;  // 18432 bf16 packed weights

    k_prep<<<72, 256, 0, stream>>>(We0, We1, We2, Wn0, Wn1, Wn2, wp);
    k_fused<<<G_GRAPHS, 256, 0, stream>>>(x, Wg0, bg0, Wg1, bg1, Wg2, bg2,
                                          wp, be0, be1, be2, bn0, bn1, bn2,
                                          hout, X);
}

// Round 6
// 208.968 us; speedup vs baseline: 1.3999x; 1.0032x over previous
//
#include <hip/hip_runtime.h>

// Problem constants
#define G_GRAPHS 1024
#define N_NODES  40
#define M_EDGES  780          // N*(N-1)/2
#define NUM_NODES (G_GRAPHS * N_NODES)          // 40960
#define H_ELEMS  (NUM_NODES * 64)               // 2621440
#define X_STRIDE 160
#define X_PER_G  25600
#define SLOPE 0.1f

#define PACK_PER_MLP 9216     // W0(4096) + W1(4096) + W2(1024) bf16 elems

typedef __bf16 bf16x8 __attribute__((ext_vector_type(8)));
typedef unsigned short us8 __attribute__((ext_vector_type(8)));
typedef float f32x4 __attribute__((ext_vector_type(4)));

__device__ __forceinline__ float lrelu(float v) { return fmaxf(v, SLOPE * v); }
__device__ __forceinline__ unsigned short f2bf(float x) {
    __bf16 b = (__bf16)x;                       // RNE convert
    return __builtin_bit_cast(unsigned short, b);
}
__device__ __forceinline__ unsigned int pk2bf(float a, float b) {
    return (unsigned int)f2bf(a) | ((unsigned int)f2bf(b) << 16);
}

// ---------------------------------------------------------------------------
// K0: pack MLP weights (bf16) in d_ws. Layout serves the A-frag role:
// element for lane l, reg j, tile (mt,kt) of W^T is
// W[kt*32 + ((l>>4)&3)*8 + j][mt*16 + (l&15)]  -> linear ((mt*2+kt)*64+l)*8+j.
// W2 padded 10->16 cols (zeros). [0..9215] edge MLP, [9216..18431] node MLP.
// ---------------------------------------------------------------------------
__global__ __launch_bounds__(256) void k_prep(const float* __restrict__ We0,
                                              const float* __restrict__ We1,
                                              const float* __restrict__ We2,
                                              const float* __restrict__ Wn0,
                                              const float* __restrict__ Wn1,
                                              const float* __restrict__ Wn2,
                                              unsigned short* __restrict__ wp) {
    int t = blockIdx.x * 256 + threadIdx.x;     // 0..18431 (72 blocks)
    int mlp = t / PACK_PER_MLP;
    int o = t - mlp * PACK_PER_MLP;
    const float* W0 = mlp ? Wn0 : We0;
    const float* W1 = mlp ? Wn1 : We1;
    const float* W2 = mlp ? Wn2 : We2;
    float val;
    if (o < 8192) {
        const float* W = (o < 4096) ? W0 : W1;
        int idx = o & 4095;
        int j = idx & 7, l = (idx >> 3) & 63, tt = idx >> 9;   // tt = mt*2+kt
        int kt = tt & 1, mt = tt >> 1;
        int k = kt * 32 + ((l >> 4) & 3) * 8 + j;
        int m = mt * 16 + (l & 15);
        val = W[k * 64 + m];
    } else {
        int idx = o - 8192;                      // 0..1023, mt=0 only
        int j = idx & 7, l = (idx >> 3) & 63, kt = idx >> 9;
        int k = kt * 32 + ((l >> 4) & 3) * 8 + j;
        int m = l & 15;
        val = (m < 10) ? W2[k * 10 + m] : 0.f;
    }
    wp[mlp * PACK_PER_MLP + o] = f2bf(val);
}

// ---------------------------------------------------------------------------
// MLP machinery. Round-6 changes (VALU diet; memory path byte-identical to
// round 5 which measured FETCH 1.8 MB / WRITE 112.6 MB = ideal):
//  - edge (i,j) decode via sIJ LDS table (1 ds_read_u16) instead of ~20-op
//    closed form with sqrt, per thread per chunk.
//  - bias as MFMA C-input: acc initialized to bias, post-MFMA adds removed.
// ---------------------------------------------------------------------------
struct ChunkRegs {
    bf16x8 A1[4][2];
    bf16x8 A2[4][2];
    bf16x8 A3[2];
    float4 bv0[4];
    float4 bv1[4];
    float  bz[4];
};

__device__ __forceinline__ void run_pair(int R0A, int R0B, int w, int l,
                                         const float4* sh4,
                                         unsigned short* sBA,
                                         unsigned short* sBB,
                                         float* sEP,
                                         const unsigned short* sIJ,
                                         const ChunkRegs& cr) {
    const int nl = l & 15;
    const int rq = (l >> 4) & 3;
    const int rl = l >> 1;            // row within wave's 32-row slice
    const int hf2 = l & 1;            // feature half

    // ---- decode both rows (table lookup) ----
    auto decode = [&](int row, int& ii, int& jj, bool& is_e, bool& is_n) {
        is_e = (row < 780);
        is_n = (row >= 800 && row < 840);
        ii = 0; jj = 0;
        if (is_e) {
            unsigned short e = sIJ[row];
            ii = e >> 8; jj = e & 255;
        } else if (is_n) {
            ii = jj = row - 800;
        }                              // else dummy row
    };
    int iiA, jjA, iiB, jjB; bool ieA, inA, ieB, inB;
    decode(R0A + rl, iiA, jjA, ieA, inA);
    decode(R0B + rl, iiB, jjB, ieB, inB);

    // ---- E build (A then B; independent chains) ----
    auto ebuild = [&](unsigned short* sB, int ii, int jj, bool is_e) {
        unsigned short tmp[32];
#pragma unroll
        for (int q = 0; q < 8; q++) {
            int u = hf2 * 8 + q;
            float4 a = sh4[ii * 16 + (u ^ ((ii & 7) << 1))];
            if (is_e) {
                float4 bq = sh4[jj * 16 + (u ^ ((jj & 7) << 1))];
                a.x += bq.x; a.y += bq.y; a.z += bq.z; a.w += bq.w;
            }
            tmp[4 * q + 0] = f2bf(a.x); tmp[4 * q + 1] = f2bf(a.y);
            tmp[4 * q + 2] = f2bf(a.z); tmp[4 * q + 3] = f2bf(a.w);
        }
        int r_sb = 32 * w + rl;
#pragma unroll
        for (int q = 0; q < 4; q++) {
            int cs = (hf2 * 4 + q) ^ (r_sb & 7);
            *(us8*)((char*)sB + r_sb * 128 + cs * 16) = *(const us8*)(tmp + 8 * q);
        }
    };
    ebuild(sBA, iiA, jjA, ieA);
    ebuild(sBB, iiB, jjB, ieB);

    // B-frag read / Z store helpers (same swizzle as rounds 0-5)
    auto ZB = [&](const unsigned short* s, int nt, int kt) -> bf16x8 {
        int node = 32 * w + nt * 16 + nl;
        int cs = (kt * 4 + rq) ^ (node & 7);
        return __builtin_bit_cast(bf16x8,
            *(const us8*)((const char*)s + node * 128 + cs * 16));
    };
    auto zstore = [&](unsigned short* s, int mt, int nt, const f32x4& v) {
        int node = 32 * w + nt * 16 + nl;
        int cs = (mt * 2 + (rq >> 1)) ^ (node & 7);
        uint2 u = make_uint2(pk2bf(v[0], v[1]), pk2bf(v[2], v[3]));
        *(uint2*)((char*)s + node * 128 + cs * 16 + (rq & 1) * 8) = u;
    };

    auto gemm_layer = [&](unsigned short* s, const bf16x8 A[4][2],
                          const float4* bv) {
        bf16x8 B[2][2];
#pragma unroll
        for (int nt = 0; nt < 2; nt++)
#pragma unroll
            for (int kt = 0; kt < 2; kt++) B[nt][kt] = ZB(s, nt, kt);
#pragma unroll
        for (int mt = 0; mt < 4; mt++) {
            float4 b = bv[mt];
#pragma unroll
            for (int nt = 0; nt < 2; nt++) {
                f32x4 acc = (f32x4){b.x, b.y, b.z, b.w};   // bias as C-input
                acc = __builtin_amdgcn_mfma_f32_16x16x32_bf16(A[mt][0], B[nt][0], acc, 0, 0, 0);
                acc = __builtin_amdgcn_mfma_f32_16x16x32_bf16(A[mt][1], B[nt][1], acc, 0, 0, 0);
                f32x4 z;
                z[0] = lrelu(acc[0]); z[1] = lrelu(acc[1]);
                z[2] = lrelu(acc[2]); z[3] = lrelu(acc[3]);
                zstore(s, mt, nt, z);
            }
        }
    };

    // ---- GEMM1 (Z1), GEMM2 (Z2): A then B per layer ----
    gemm_layer(sBA, cr.A1, cr.bv0);
    gemm_layer(sBB, cr.A1, cr.bv0);
    gemm_layer(sBA, cr.A2, cr.bv1);
    gemm_layer(sBB, cr.A2, cr.bv1);

    // ---- GEMM3: EP -> sEP (f32, stride 10), both chains ----
    auto gemm3 = [&](unsigned short* s, int R0) {
        bf16x8 B[2][2];
#pragma unroll
        for (int nt = 0; nt < 2; nt++)
#pragma unroll
            for (int kt = 0; kt < 2; kt++) B[nt][kt] = ZB(s, nt, kt);
#pragma unroll
        for (int nt = 0; nt < 2; nt++) {
            f32x4 acc = (f32x4){cr.bz[0], cr.bz[1], cr.bz[2], cr.bz[3]};
            acc = __builtin_amdgcn_mfma_f32_16x16x32_bf16(cr.A3[0], B[nt][0], acc, 0, 0, 0);
            acc = __builtin_amdgcn_mfma_f32_16x16x32_bf16(cr.A3[1], B[nt][1], acc, 0, 0, 0);
            int rowe = R0 + nt * 16 + nl;
            bool valid = (rowe < 780) || (rowe >= 800 && rowe < 840);
            if (valid && rq < 3) {
                int epr = (rowe < 780) ? rowe : rowe - 20;   // nodes -> 780..819
                float* p = sEP + epr * 10 + rq * 4;
                *(float2*)p = make_float2(acc[0], acc[1]);
                if (rq < 2)
                    *(float2*)(p + 2) = make_float2(acc[2], acc[3]);
            }
        }
    };
    gemm3(sBA, R0A);
    gemm3(sBB, R0B);
}

// ---------------------------------------------------------------------------
// K1 (fused): GCN + pair-ILP MLP + coalesced X sweep, one graph per block.
// LDS arena (77,408 B, 2 blocks/CU):
//   [0,     10240)  sh   : final h, 40x64 f32, swizzled | GCN: h0@0
//   [10240, 26624)  sBA  : chain-A GEMM ping            | GCN: buf@10240,
//                                                         h1@20480
//   [26624, 43008)  sBB  : chain-B GEMM ping            | GCN: h2@26624
//   [43008, 75808)  sEP  : 820x10 f32 MLP outputs       | GCN: P@43008
//   [75808, 77368)  sIJ  : edge (i<<8|j) decode table
// Round-6: GCN reduce loses the tid<32 S-stage (every thread sums its own
// P rows after the P barrier; 14 -> 10 barriers). P lives in the sEP alias,
// OUTSIDE sh, so the epilogue's sh writes cannot race the P reads.
// ---------------------------------------------------------------------------
__global__ __launch_bounds__(256, 2) void k_fused(const float* __restrict__ x,
                                                  const float* __restrict__ Wg0,
                                                  const float* __restrict__ bg0,
                                                  const float* __restrict__ Wg1,
                                                  const float* __restrict__ bg1,
                                                  const float* __restrict__ Wg2,
                                                  const float* __restrict__ bg2,
                                                  const unsigned short* __restrict__ wp,
                                                  const float* __restrict__ be0,
                                                  const float* __restrict__ be1,
                                                  const float* __restrict__ be2,
                                                  const float* __restrict__ bn0,
                                                  const float* __restrict__ bn1,
                                                  const float* __restrict__ bn2,
                                                  float* __restrict__ hout,
                                                  float* __restrict__ X) {
    __shared__ __align__(16) char smem[77408];
    float* sh           = (float*)smem;                      // [0,10240)
    unsigned short* sBA = (unsigned short*)(smem + 10240);   // [10240,26624)
    unsigned short* sBB = (unsigned short*)(smem + 26624);   // [26624,43008)
    float* sEP          = (float*)(smem + 43008);            // [43008,75808)
    unsigned short* sIJ = (unsigned short*)(smem + 75808);   // [75808,77368)
    // GCN-phase aliases
    float* h0  = (float*)smem;                               // [0,960)
    float* buf = (float*)(smem + 10240);                     // [10240,20480)
    float* h1  = (float*)(smem + 20480);                     // [20480,25600)
    float* h2  = (float*)(smem + 26624);                     // [26624,31744)
    float* P   = (float*)(smem + 43008);                     // [43008,45056)

    const int g = blockIdx.x;
    const int tid = threadIdx.x;
    const int l = tid & 63;
    const int w = tid >> 6;
    const float inv39 = 1.0f / 39.0f;
    const int c32 = tid & 31;
    const int c64 = tid & 63;
    const int rq = (l >> 4) & 3;

    // ---- build edge decode table (once per block; covered by GCN bar #1) --
    for (int m = tid; m < 780; m += 256) {
        float tq = 6241.0f - 8.0f * (float)m;      // exact in fp32
        int i0 = (int)(0.5f * (79.0f - sqrtf(tq)));
        i0 = min(38, max(0, i0));
        int cum = 39 * i0 - ((i0 * (i0 - 1)) >> 1);
        if (cum > m) { --i0; cum = 39 * i0 - ((i0 * (i0 - 1)) >> 1); }
        else if (m - cum >= 39 - i0) { cum += 39 - i0; ++i0; }
        int jj = i0 + 1 + (m - cum);
        sIJ[m] = (unsigned short)((i0 << 8) | jj);
    }

    // =========================== GCN phase ===========================
    {
        float w0c[6], w1c[32], w2c[32];
#pragma unroll
        for (int f = 0; f < 6; f++)  w0c[f] = Wg0[f * 32 + c32];
#pragma unroll
        for (int m = 0; m < 32; m++) w1c[m] = Wg1[m * 32 + c32];
#pragma unroll
        for (int m = 0; m < 32; m++) w2c[m] = Wg2[m * 64 + c64];
        const float b0c = bg0[c32];
        const float b1c = bg1[c32];
        const float b2c = bg2[c64];

        for (int idx = tid; idx < N_NODES * 6; idx += 256) {
            int n = idx / 6, f = idx - n * 6;
            h0[idx] = x[(g * N_NODES + n) * 16 + f];
        }
        __syncthreads();                                      // bar 1

        // ---- layer 0 ----
        {
            int n0 = tid >> 5;
#pragma unroll
            for (int t = 0; t < 5; t++) {
                int n = n0 + 8 * t;
                float s = 0.f;
#pragma unroll
                for (int f = 0; f < 6; f++) s += h0[n * 6 + f] * w0c[f];
                buf[n * 32 + c32] = s;
            }
        }
        __syncthreads();                                      // bar 2
        { int grp = tid >> 5; float s = 0.f;
#pragma unroll
          for (int n = grp * 5; n < grp * 5 + 5; n++) s += buf[n * 32 + c32];
          P[grp * 32 + c32] = s; }
        __syncthreads();                                      // bar 3
        { float s0 = 0.f;
#pragma unroll
          for (int grp = 0; grp < 8; grp++) s0 += P[grp * 32 + c32];
          for (int idx = tid; idx < N_NODES * 32; idx += 256)
              h1[idx] = lrelu((s0 - buf[idx]) * inv39 + b0c); }
        __syncthreads();                                      // bar 4

        // ---- layer 1 ----
        {
            int n0 = tid >> 5;
#pragma unroll
            for (int t = 0; t < 5; t++) {
                int n = n0 + 8 * t;
                const float4* hp = (const float4*)(h1 + n * 32);
                float s = 0.f;
#pragma unroll
                for (int q = 0; q < 8; q++) {
                    float4 hv = hp[q];
                    s += hv.x * w1c[4 * q + 0] + hv.y * w1c[4 * q + 1]
                       + hv.z * w1c[4 * q + 2] + hv.w * w1c[4 * q + 3];
                }
                buf[n * 32 + c32] = s;
            }
        }
        __syncthreads();                                      // bar 5
        { int grp = tid >> 5; float s = 0.f;
#pragma unroll
          for (int n = grp * 5; n < grp * 5 + 5; n++) s += buf[n * 32 + c32];
          P[grp * 32 + c32] = s; }
        __syncthreads();                                      // bar 6
        { float s0 = 0.f;
#pragma unroll
          for (int grp = 0; grp < 8; grp++) s0 += P[grp * 32 + c32];
          for (int idx = tid; idx < N_NODES * 32; idx += 256)
              h2[idx] = lrelu((s0 - buf[idx]) * inv39 + b1c); }
        __syncthreads();                                      // bar 7

        // ---- layer 2 ----
        {
            int n0 = tid >> 6;
#pragma unroll
            for (int t = 0; t < 10; t++) {
                int n = n0 + 4 * t;
                const float4* hp = (const float4*)(h2 + n * 32);
                float s = 0.f;
#pragma unroll
                for (int q = 0; q < 8; q++) {
                    float4 hv = hp[q];
                    s += hv.x * w2c[4 * q + 0] + hv.y * w2c[4 * q + 1]
                       + hv.z * w2c[4 * q + 2] + hv.w * w2c[4 * q + 3];
                }
                buf[n * 64 + c64] = s;
            }
        }
        __syncthreads();                                      // bar 8
        { int grp = tid >> 6; float s = 0.f;
#pragma unroll
          for (int n = grp * 10; n < grp * 10 + 10; n++) s += buf[n * 64 + c64];
          P[grp * 64 + c64] = s; }
        __syncthreads();                                      // bar 9

        // ---- epilogue: write hout (global) + sh (LDS, swizzled) ----
        // (P @43008 is outside sh -> no race; clobbers only dead h0 region)
        { float s0 = 0.f;
#pragma unroll
          for (int grp = 0; grp < 4; grp++) s0 += P[grp * 64 + c64];
          for (int idx = tid; idx < N_NODES * 64; idx += 256) {
              float v = (s0 - buf[idx]) * inv39 + b2c;
              hout[g * N_NODES * 64 + idx] = v;
              int n = idx >> 6;
              int u = c64 >> 2;
              int us = u ^ ((n & 7) << 1);
              sh[n * 64 + us * 4 + (c64 & 3)] = v;
          } }
    }
    __syncthreads();   // bar 10: sh + sIJ ready; GCN scratch dead

    // =========================== MLP phase ===========================
    const float4* sh4 = (const float4*)sh;

    auto WA = [&](const unsigned short* base, int mt, int kt) -> bf16x8 {
        return __builtin_bit_cast(bf16x8,
            *(const us8*)(base + ((mt * 2 + kt) * 64 + l) * 8));
    };
    auto loadW = [&](ChunkRegs& cr, const unsigned short* wb,
                     const float* B0, const float* B1, const float* B2) {
#pragma unroll
        for (int mt = 0; mt < 4; mt++) {
#pragma unroll
            for (int kt = 0; kt < 2; kt++) {
                cr.A1[mt][kt] = WA(wb, mt, kt);
                cr.A2[mt][kt] = WA(wb + 4096, mt, kt);
            }
            cr.bv0[mt] = *(const float4*)(B0 + mt * 16 + rq * 4);
            cr.bv1[mt] = *(const float4*)(B1 + mt * 16 + rq * 4);
        }
        cr.A3[0] = WA(wb + 8192, 0, 0);
        cr.A3[1] = WA(wb + 8192, 0, 1);
#pragma unroll
        for (int k = 0; k < 4; k++) {
            int f = rq * 4 + k;
            cr.bz[k] = (f < 10) ? B2[f] : 0.f;
        }
    };

    ChunkRegs ce;
    loadW(ce, wp, be0, be1, be2);            // edge MLP weights

    // pair loop: wave-local, no barriers. p=13 (node pair) is always wave
    // 1's LAST pair -> overwrite ce with node weights in place.
    for (int p = w; p < 14; p += 4) {
        int c1, c2;
        if (p < 12)       { c1 = 2 * p; c2 = 2 * p + 1; }   // edge pairs
        else if (p == 12) { c1 = 24;    c2 = 27;        }   // edge + dummy
        else              { c1 = 25;    c2 = 26;            // node pair
                            loadW(ce, wp + PACK_PER_MLP, bn0, bn1, bn2); }
        run_pair(32 * c1, 32 * c2, w, l, sh4, sBA, sBB, sEP, sIJ, ce);
    }

    __syncthreads();   // all EP rows ready

    // ---- X sweep: thread owns whole 4x4 blocks; coalesced stores ----
    float* Xg = X + g * X_PER_G;
#pragma unroll
    for (int k = 0; k < 7; k++) {
        int b = k * 256 + tid;
        if (b < 1600) {
            int bi = b / 40;
            int bj = b - bi * 40;
            int ridx;
            if (bi == bj) {
                ridx = 780 + bi;
            } else {
                int mn = min(bi, bj), mx = max(bi, bj);
                ridx = 39 * mn - ((mn * (mn - 1)) >> 1) + (mx - mn - 1);
            }
            const float* ep = sEP + ridx * 10;
            float2 e0 = *(const float2*)(ep + 0);
            float2 e1 = *(const float2*)(ep + 2);
            float2 e2 = *(const float2*)(ep + 4);
            float2 e3 = *(const float2*)(ep + 6);
            float2 e4 = *(const float2*)(ep + 8);
            float f0 = e0.x, f1 = e0.y, f2 = e1.x, f3 = e1.y;
            float f4 = e2.x, f5 = e2.y, f6 = e3.x, f7 = e3.y;
            float f8 = e4.x, f9 = e4.y;
            float4 r0 = make_float4(f0, f1, f2, f3);
            float4 r1 = make_float4(f1, f4, f5, f6);
            float4 r2 = make_float4(f2, f5, f7, f8);
            float4 r3 = make_float4(f3, f6, f8, f9);
            float* p = Xg + (4 * bi) * X_STRIDE + 4 * bj;
            *(float4*)(p + 0 * X_STRIDE) = r0;
            *(float4*)(p + 1 * X_STRIDE) = r1;
            *(float4*)(p + 2 * X_STRIDE) = r2;
            *(float4*)(p + 3 * X_STRIDE) = r3;
        }
    }
}

// ---------------------------------------------------------------------------
// Launch
// ---------------------------------------------------------------------------
extern "C" void kernel_launch(void* const* d_in, const int* in_sizes, int n_in,
                              void* d_out, int out_size, void* d_ws, size_t ws_size,
                              hipStream_t stream) {
    const float* x   = (const float*)d_in[0];
    const float* Wg0 = (const float*)d_in[4];
    const float* bg0 = (const float*)d_in[5];
    const float* Wg1 = (const float*)d_in[6];
    const float* bg1 = (const float*)d_in[7];
    const float* Wg2 = (const float*)d_in[8];
    const float* bg2 = (const float*)d_in[9];
    const float* Wn0 = (const float*)d_in[10];
    const float* bn0 = (const float*)d_in[11];
    const float* Wn1 = (const float*)d_in[12];
    const float* bn1 = (const float*)d_in[13];
    const float* Wn2 = (const float*)d_in[14];
    const float* bn2 = (const float*)d_in[15];
    const float* We0 = (const float*)d_in[16];
    const float* be0 = (const float*)d_in[17];
    const float* We1 = (const float*)d_in[18];
    const float* be1 = (const float*)d_in[19];
    const float* We2 = (const float*)d_in[20];
    const float* be2 = (const float*)d_in[21];

    float* hout = (float*)d_out;            // h: 40960 x 64 fp32
    float* X    = hout + H_ELEMS;           // X: 1024 x 160 x 160 fp32
    unsigned short* wp = (unsigned short*)d_ws;  // 18432 bf16 packed weights

    k_prep<<<72, 256, 0, stream>>>(We0, We1, We2, Wn0, Wn1, Wn2, wp);
    k_fused<<<G_GRAPHS, 256, 0, stream>>>(x, Wg0, bg0, Wg1, bg1, Wg2, bg2,
                                          wp, be0, be1, be2, bn0, bn1, bn2,
                                          hout, X);
}